// Round 10
// baseline (7239.958 us; speedup 1.0000x reference)
//
#include <hip/hip_runtime.h>
#include <math.h>

// Neural Turing Machine forward, fully fused persistent kernel.
// R10: overlap the L2-BW-bound z-GEMM with the latency-bound addressing
// chain. Measured (R9/R6): step = ~21K cy weight streaming (VALU idle) +
// ~20-25K cy serial addressing (L2 idle), executed back-to-back = 61K cy.
// z(t+1) = h(t)@Wr + xcat(t+1)@Wk + b, and h(t) is final after P2(t) -> the
// 1 MB h@Wr stream is computed in 8 register-accumulating chunks placed
// inside the 8 addressing phase regions (loads -> registers cross barriers;
// T14-verified). P1 keeps only the 0.16 MB xcat@Wk part. Also merged the
// content-softmax max phase (exp directly; bs bounded <<88) -> 11 barriers.
// Topology unchanged: 256 blocks x 512 threads, G=2, 1 block/CU.

#define NSLOT  256
#define MU     32
#define MPAD   33      // +1 pad: M row scalar reads are 2-way/bank = free
#define TSTEPS 64
#define EPSF   1e-8f

__device__ __forceinline__ float sigf(float x){ return 1.0f/(1.0f + expf(-x)); }
__device__ __forceinline__ float softplusf_(float x){ return fmaxf(x,0.0f) + log1pf(expf(-fabsf(x))); }

// paired 64-lane butterfly sum (two independent values per lane)
__device__ __forceinline__ void wred_sum2(float& a, float& b){
  #pragma unroll
  for (int m = 32; m >= 1; m >>= 1){ a += __shfl_xor(a, m, 64); b += __shfl_xor(b, m, 64); }
}

struct __align__(16) Smem {
  float M[2][NSLOT][MPAD];   // 67.6 KB, padded rows
  float zp[2][2][1024];      // z partials [khalf][g][col], 16 KB
  float h[2][256];           // 16B-aligned
  float c[2][256];
  float hob[2][140];         // [read ho(38) | write wo(102)]
  float xcat[2][40];         // [x(8) | R(32)]  (16B-aligned)
  float wr[2][NSLOT];        // read weights state
  float ww[2][NSLOT];        // write weights state
  float wg[2][2][NSLOT];     // gated weights scratch [head][g][slot]
  float k[2][2][MU];         // keys [head][g][m]
  float kn2[2][2];           // key norms [head][g]
  float E[2][MU];
  float A[2][MU];
  float R[2][MU];
  float rpart[2][8][MU];     // read-vector partials [g][chunk][m]
  float red[4][8];           // reduction slots [site][wave]
};  // ~101 KB -> 1 block/CU

// One 4-row slab of the h@Wr GEMM for step t+1, accumulating into the
// persistent registers a0x..a1w. Reads Wr (global->reg) and s.h (stable
// between P2(t) and P2(t+1)). No LDS writes -> legal in any region.
#define Z_BODY(r) { \
  const float4 h0_ = *(const float4*)&s.h[0][(r)]; \
  const float4 h1_ = *(const float4*)&s.h[1][(r)]; \
  const float4 w0_ = *(const float4*)&Wr[((r)+0)*1024 + c0]; \
  const float4 w1_ = *(const float4*)&Wr[((r)+1)*1024 + c0]; \
  const float4 w2_ = *(const float4*)&Wr[((r)+2)*1024 + c0]; \
  const float4 w3_ = *(const float4*)&Wr[((r)+3)*1024 + c0]; \
  a0x=fmaf(w0_.x,h0_.x,a0x); a0y=fmaf(w0_.y,h0_.x,a0y); a0z=fmaf(w0_.z,h0_.x,a0z); a0w=fmaf(w0_.w,h0_.x,a0w); \
  a1x=fmaf(w0_.x,h1_.x,a1x); a1y=fmaf(w0_.y,h1_.x,a1y); a1z=fmaf(w0_.z,h1_.x,a1z); a1w=fmaf(w0_.w,h1_.x,a1w); \
  a0x=fmaf(w1_.x,h0_.y,a0x); a0y=fmaf(w1_.y,h0_.y,a0y); a0z=fmaf(w1_.z,h0_.y,a0z); a0w=fmaf(w1_.w,h0_.y,a0w); \
  a1x=fmaf(w1_.x,h1_.y,a1x); a1y=fmaf(w1_.y,h1_.y,a1y); a1z=fmaf(w1_.z,h1_.y,a1z); a1w=fmaf(w1_.w,h1_.y,a1w); \
  a0x=fmaf(w2_.x,h0_.z,a0x); a0y=fmaf(w2_.y,h0_.z,a0y); a0z=fmaf(w2_.z,h0_.z,a0z); a0w=fmaf(w2_.w,h0_.z,a0w); \
  a1x=fmaf(w2_.x,h1_.z,a1x); a1y=fmaf(w2_.y,h1_.z,a1y); a1z=fmaf(w2_.z,h1_.z,a1z); a1w=fmaf(w2_.w,h1_.z,a1w); \
  a0x=fmaf(w3_.x,h0_.w,a0x); a0y=fmaf(w3_.y,h0_.w,a0y); a0z=fmaf(w3_.z,h0_.w,a0z); a0w=fmaf(w3_.w,h0_.w,a0w); \
  a1x=fmaf(w3_.x,h1_.w,a1x); a1y=fmaf(w3_.y,h1_.w,a1y); a1z=fmaf(w3_.z,h1_.w,a1z); a1w=fmaf(w3_.w,h1_.w,a1w); \
}

// 16 rows (4 bodies) per region; 8 regions x 16 = this q-half's 128 rows.
// Skipped on the last step (z(T) is never consumed).
#define Z_CHUNK(i) \
  if (t < TSTEPS-1) { \
    const int zr_ = zbase + (i)*16; \
    Z_BODY(zr_); Z_BODY(zr_+4); Z_BODY(zr_+8); Z_BODY(zr_+12); \
  }

__global__ __launch_bounds__(512)
void ntm_fused(const float* __restrict__ X,
               const float* __restrict__ Wk,   const float* __restrict__ Wr,
               const float* __restrict__ Lb,
               const float* __restrict__ rW,   const float* __restrict__ rb,
               const float* __restrict__ wW,   const float* __restrict__ wb,
               const float* __restrict__ oW,   const float* __restrict__ ob,
               const float* __restrict__ rInit,
               const float* __restrict__ wrI,  const float* __restrict__ wwI,
               float* __restrict__ Y)
{
  __shared__ Smem s;

  const int tid  = threadIdx.x;
  const int q    = tid >> 8;        // k-half for z-GEMM
  const int n2   = tid & 255;       // col-group / unit / slot index
  const int g2   = tid >> 8;        // batch slot for per-element phases
  const int wave = tid >> 6;        // 0..7
  const int lane = tid & 63;
  const int wb0  = g2 * 4;          // first wave of this element's group
  const int bB   = blockIdx.x * 2;  // first batch element of this block
  const int c0   = n2 * 4;          // this thread's 4 z-columns
  const int zbase = q * 128;        // this q-half's Wr rows: 128 each

  // persistent z accumulators: hold h(t)@Wr partial for step t+1
  float a0x=0.f,a0y=0.f,a0z=0.f,a0w=0.f;
  float a1x=0.f,a1y=0.f,a1z=0.f,a1w=0.f;

  // ---------------- init state ----------------
  {
    for (int m = 0; m < MU; ++m) s.M[g2][n2][m] = 1e-6f;
    s.h[g2][n2] = 0.0f;
    s.c[g2][n2] = 0.0f;
    if (n2 < MU) s.R[g2][n2] = tanhf(rInit[n2]);
    if (n2 < 40)
      s.xcat[g2][n2] = (n2 < 8) ? X[((bB + g2)*TSTEPS + 0)*8 + n2]
                                : tanhf(rInit[n2 - 8]);
    // initial weight softmaxes (once; serial per thread, broadcast reads)
    float mx = -1e30f;
    for (int i = 0; i < NSLOT; ++i) mx = fmaxf(mx, wrI[i]);
    float sm = 0.0f;
    for (int i = 0; i < NSLOT; ++i) sm += expf(wrI[i] - mx);
    s.wr[g2][n2] = expf(wrI[n2] - mx) / sm;
    mx = -1e30f;
    for (int i = 0; i < NSLOT; ++i) mx = fmaxf(mx, wwI[i]);
    sm = 0.0f;
    for (int i = 0; i < NSLOT; ++i) sm += expf(wwI[i] - mx);
    s.ww[g2][n2] = expf(wwI[n2] - mx) / sm;
  }
  __syncthreads();

  // ---------------- time loop (11 barriers/step) ----------------
  for (int t = 0; t < TSTEPS; ++t) {
    // ---- P1: z finish = zacc (h@Wr from prev iter) + xcat@Wk (q0) ----
    {
      if (q == 0) {
        #pragma unroll 2
        for (int i4 = 0; i4 < 10; ++i4) {
          const int r = i4*4;
          float4 x0 = *(const float4*)&s.xcat[0][r];
          float4 x1 = *(const float4*)&s.xcat[1][r];
          float4 w0 = *(const float4*)&Wk[(r+0)*1024 + c0];
          float4 w1 = *(const float4*)&Wk[(r+1)*1024 + c0];
          float4 w2 = *(const float4*)&Wk[(r+2)*1024 + c0];
          float4 w3 = *(const float4*)&Wk[(r+3)*1024 + c0];
          a0x=fmaf(w0.x,x0.x,a0x); a0y=fmaf(w0.y,x0.x,a0y); a0z=fmaf(w0.z,x0.x,a0z); a0w=fmaf(w0.w,x0.x,a0w);
          a1x=fmaf(w0.x,x1.x,a1x); a1y=fmaf(w0.y,x1.x,a1y); a1z=fmaf(w0.z,x1.x,a1z); a1w=fmaf(w0.w,x1.x,a1w);
          a0x=fmaf(w1.x,x0.y,a0x); a0y=fmaf(w1.y,x0.y,a0y); a0z=fmaf(w1.z,x0.y,a0z); a0w=fmaf(w1.w,x0.y,a0w);
          a1x=fmaf(w1.x,x1.y,a1x); a1y=fmaf(w1.y,x1.y,a1y); a1z=fmaf(w1.z,x1.y,a1z); a1w=fmaf(w1.w,x1.y,a1w);
          a0x=fmaf(w2.x,x0.z,a0x); a0y=fmaf(w2.y,x0.z,a0y); a0z=fmaf(w2.z,x0.z,a0z); a0w=fmaf(w2.w,x0.z,a0w);
          a1x=fmaf(w2.x,x1.z,a1x); a1y=fmaf(w2.y,x1.z,a1y); a1z=fmaf(w2.z,x1.z,a1z); a1w=fmaf(w2.w,x1.z,a1w);
          a0x=fmaf(w3.x,x0.w,a0x); a0y=fmaf(w3.y,x0.w,a0y); a0z=fmaf(w3.z,x0.w,a0z); a0w=fmaf(w3.w,x0.w,a0w);
          a1x=fmaf(w3.x,x1.w,a1x); a1y=fmaf(w3.y,x1.w,a1y); a1z=fmaf(w3.z,x1.w,a1z); a1w=fmaf(w3.w,x1.w,a1w);
        }
      }
      *(float4*)&s.zp[q][0][c0] = make_float4(a0x,a0y,a0z,a0w);
      *(float4*)&s.zp[q][1][c0] = make_float4(a1x,a1y,a1z,a1w);
      a0x=0.f; a0y=0.f; a0z=0.f; a0w=0.f;
      a1x=0.f; a1y=0.f; a1z=0.f; a1w=0.f;
    }
    __syncthreads();                                   // bar 1

    // ---- P2: LSTM gates (keras i,f,g,o); Z==h since |h|<1<CLIP ----
    {
      float zi = s.zp[0][g2][n2      ] + s.zp[1][g2][n2      ] + Lb[n2      ];
      float zf = s.zp[0][g2][n2 + 256] + s.zp[1][g2][n2 + 256] + Lb[n2 + 256];
      float zg = s.zp[0][g2][n2 + 512] + s.zp[1][g2][n2 + 512] + Lb[n2 + 512];
      float zo = s.zp[0][g2][n2 + 768] + s.zp[1][g2][n2 + 768] + Lb[n2 + 768];
      float cn = sigf(zf)*s.c[g2][n2] + sigf(zi)*tanhf(zg);
      float hn = sigf(zo)*tanhf(cn);
      s.c[g2][n2] = cn;
      s.h[g2][n2] = hn;
    }
    __syncthreads();                                   // bar 2
    // ---- h(t) final in LDS: Wr chunks for z(t+1) start flowing below ----

    // ---- P3: head outputs ho = h @ [read_W | write_W] + bias ----
    if (tid < 280) {
      const int g  = tid / 140;
      const int cc = tid % 140;
      const float* Wp; int stride, c; float acc;
      if (cc < 38) { Wp = rW; stride = 38;  c = cc;      acc = rb[c]; }
      else         { Wp = wW; stride = 102; c = cc - 38; acc = wb[c]; }
      #pragma unroll 4
      for (int r4 = 0; r4 < 64; ++r4) {
        const int r = r4*4;
        float4 hv = *(const float4*)&s.h[g][r];
        acc = fmaf(Wp[(r+0)*stride + c], hv.x, acc);
        acc = fmaf(Wp[(r+1)*stride + c], hv.y, acc);
        acc = fmaf(Wp[(r+2)*stride + c], hv.z, acc);
        acc = fmaf(Wp[(r+3)*stride + c], hv.w, acc);
      }
      s.hob[g][cc] = acc;
    }
    Z_CHUNK(0);
    __syncthreads();                                   // bar 3

    // ---- P4: keys + key norms (in-wave) + E/A vectors ----
    if (n2 < 64) {
      const int half = n2 >> 5;           // 0: read key, 1: write key
      const int m    = n2 & 31;
      float kv = tanhf(s.hob[g2][half*38 + m]);
      s.k[half][g2][m] = kv;
      float p = kv*kv;
      #pragma unroll
      for (int mm_ = 16; mm_ >= 1; mm_ >>= 1) p += __shfl_xor(p, mm_, 64);
      if (m == 0) s.kn2[half][g2] = sqrtf(p);
    } else if (n2 < 96) {
      const int m = n2 & 31;
      s.E[g2][m] = sigf(s.hob[g2][76 + m]);
    } else if (n2 < 128) {
      const int m = n2 & 31;
      s.A[g2][m] = tanhf(s.hob[g2][108 + m]);
    }
    Z_CHUNK(1);
    __syncthreads();                                   // bar 4

    // ---- P5: cosine sims (shared M row+norm) + exp + paired sum-reduce ----
    // (max-subtraction dropped: bs = beta*sim is O(few), exp cannot overflow;
    //  softmax ratio is mathematically identical)
    float exr, exw;
    {
      const float* Mr = &s.M[g2][n2][0];
      const float* kr = &s.k[0][g2][0];
      const float* kw = &s.k[1][g2][0];
      float dr = 0.f, dw = 0.f, mm = 0.f;
      #pragma unroll
      for (int m = 0; m < MU; ++m) {
        float Mv = Mr[m];
        dr = fmaf(Mv, kr[m], dr);
        dw = fmaf(Mv, kw[m], dw);
        mm = fmaf(Mv, Mv, mm);
      }
      float nM = sqrtf(mm);
      float simr = dr / (nM * s.kn2[0][g2] + EPSF);
      float simw = dw / (nM * s.kn2[1][g2] + EPSF);
      float bsr = softplusf_(s.hob[g2][32])      * simr;
      float bsw = softplusf_(s.hob[g2][38 + 32]) * simw;
      exr = expf(bsr);
      exw = expf(bsw);
      float sr = exr, sw = exw;
      wred_sum2(sr, sw);
      if (lane == 0) { s.red[0][wave] = sr; s.red[1][wave] = sw; }
    }
    Z_CHUNK(2);
    __syncthreads();                                   // bar 5

    // ---- P6: content weights + interpolation, publish for shift conv ----
    {
      float smr = s.red[0][wb0] + s.red[0][wb0+1] + s.red[0][wb0+2] + s.red[0][wb0+3];
      float smw = s.red[1][wb0] + s.red[1][wb0+1] + s.red[1][wb0+2] + s.red[1][wb0+3];
      float wcr = exr / smr;
      float wcw = exw / smw;
      float ggr = sigf(s.hob[g2][33]);
      float ggw = sigf(s.hob[g2][38 + 33]);
      s.wg[0][g2][n2] = fmaf(ggr, wcr, (1.0f - ggr) * s.wr[g2][n2]);
      s.wg[1][g2][n2] = fmaf(ggw, wcw, (1.0f - ggw) * s.ww[g2][n2]);
    }
    Z_CHUNK(3);
    __syncthreads();                                   // bar 6

    // ---- P7: shift conv + sharpen + paired sum-reduce ----
    float wpr, wpw;
    {
      float r0 = s.hob[g2][34], r1 = s.hob[g2][35], r2 = s.hob[g2][36];
      float m3 = fmaxf(r0, fmaxf(r1, r2));
      float e0 = expf(r0-m3), e1 = expf(r1-m3), e2 = expf(r2-m3);
      float iv = 1.0f/(e0+e1+e2);
      float s0r = e0*iv, s1r = e1*iv, s2r = e2*iv;
      float gmr = 1.0f + softplusf_(s.hob[g2][37]);
      r0 = s.hob[g2][38+34]; r1 = s.hob[g2][38+35]; r2 = s.hob[g2][38+36];
      m3 = fmaxf(r0, fmaxf(r1, r2));
      e0 = expf(r0-m3); e1 = expf(r1-m3); e2 = expf(r2-m3);
      iv = 1.0f/(e0+e1+e2);
      float s0w = e0*iv, s1w = e1*iv, s2w = e2*iv;
      float gmw = 1.0f + softplusf_(s.hob[g2][38+37]);

      const int np = (n2+1) & 255, nm = (n2-1) & 255;
      float wsr = s0r*s.wg[0][g2][np] + s1r*s.wg[0][g2][n2] + s2r*s.wg[0][g2][nm];
      float wsw = s0w*s.wg[1][g2][np] + s1w*s.wg[1][g2][n2] + s2w*s.wg[1][g2][nm];
      wpr = powf(wsr, gmr);
      wpw = powf(wsw, gmw);
      float sr = wpr, sw = wpw;
      wred_sum2(sr, sw);
      if (lane == 0) { s.red[2][wave] = sr; s.red[3][wave] = sw; }
    }
    Z_CHUNK(4);
    __syncthreads();                                   // bar 7

    // ---- P8: normalize -> new weight states ----
    {
      float spr = s.red[2][wb0] + s.red[2][wb0+1] + s.red[2][wb0+2] + s.red[2][wb0+3];
      float spw = s.red[3][wb0] + s.red[3][wb0+1] + s.red[3][wb0+2] + s.red[3][wb0+3];
      s.wr[g2][n2] = wpr / (spr + EPSF);
      s.ww[g2][n2] = wpw / (spw + EPSF);
    }
    Z_CHUNK(5);
    __syncthreads();                                   // bar 8

    // ---- P9: R partials = wr . M (pre-write M), 8 chunks x 32 m ----
    {
      const int chunk = n2 >> 5;
      const int m     = n2 & 31;
      const int nb    = chunk * 32;
      float acc = 0.0f;
      #pragma unroll 4
      for (int nn = 0; nn < 32; ++nn) {
        const int n = nb + nn;
        acc = fmaf(s.wr[g2][n], s.M[g2][n][m], acc);
      }
      s.rpart[g2][chunk][m] = acc;
    }
    Z_CHUNK(6);
    __syncthreads();                                   // bar 9

    // ---- P10: R finalize + memory write M = M*(1-ww*E) + ww*A ----
    if (n2 < MU) {
      float r = 0.0f;
      #pragma unroll
      for (int c = 0; c < 8; ++c) r += s.rpart[g2][c][n2];
      s.R[g2][n2] = r;
    }
    {
      const float wwn = s.ww[g2][n2];
      float* Mr = &s.M[g2][n2][0];
      #pragma unroll
      for (int m = 0; m < MU; ++m) {
        Mr[m] = Mr[m] * (1.0f - wwn*s.E[g2][m]) + wwn*s.A[g2][m];
      }
    }
    Z_CHUNK(7);
    __syncthreads();                                   // bar 10

    // ---- P11: output Y = clip([R|h]@oW + b) ; next-step xcat ----
    {
      const int o = n2 >> 5;   // 0..7
      const int l = n2 & 31;
      float acc = 0.0f;
      #pragma unroll
      for (int ss = 0; ss < 9; ++ss) {
        const int j = l + 32*ss;     // covers 0..287 exactly
        float v = (j < 32) ? s.R[g2][j] : s.h[g2][j - 32];
        acc = fmaf(v, oW[j*8 + o], acc);
      }
      #pragma unroll
      for (int m = 16; m >= 1; m >>= 1) acc += __shfl_xor(acc, m, 64);
      if (l == 0) {
        float y = acc + ob[o];
        y = fminf(fmaxf(y, -20.0f), 20.0f);
        Y[((bB + g2)*TSTEPS + t)*8 + o] = y;
      }
      if (n2 >= 8 && n2 < 40) {
        s.xcat[g2][n2] = s.R[g2][n2 - 8];
      } else if (n2 < 8 && t + 1 < TSTEPS) {
        s.xcat[g2][n2] = X[((bB + g2)*TSTEPS + (t+1))*8 + n2];
      }
    }
    __syncthreads();                                   // bar 11
  }
}

extern "C" void kernel_launch(void* const* d_in, const int* in_sizes, int n_in,
                              void* d_out, int out_size, void* d_ws, size_t ws_size,
                              hipStream_t stream)
{
  const float* X     = (const float*)d_in[0];
  const float* Wk    = (const float*)d_in[1];
  const float* Wr    = (const float*)d_in[2];
  const float* Lb    = (const float*)d_in[3];
  const float* rW    = (const float*)d_in[4];
  const float* rb    = (const float*)d_in[5];
  const float* wW    = (const float*)d_in[6];
  const float* wb    = (const float*)d_in[7];
  const float* oW    = (const float*)d_in[8];
  const float* ob    = (const float*)d_in[9];
  const float* rInit = (const float*)d_in[10];
  const float* wrI   = (const float*)d_in[11];
  const float* wwI   = (const float*)d_in[12];
  float* Y = (float*)d_out;

  hipLaunchKernelGGL(ntm_fused, dim3(256), dim3(512), 0, stream,
                     X, Wk, Wr, Lb, rW, rb, wW, wb, oW, ob, rInit, wrI, wwI, Y);
}